// Round 1
// baseline (586.387 us; speedup 1.0000x reference)
//
#include <hip/hip_runtime.h>
#include <math.h>

#define HH 256
#define WW 256
#define CC 16
#define BB 16
#define NCP 64
#define NA 67    // 64 control points + 3 affine
#define NRHS 32  // 16 batches * 2 coordinates

// ---------------------------------------------------------------------------
// Kernel 1: build the (constant) 67x67 TPS system and solve it for all 32 RHS
// columns at once via Gauss-Jordan with partial pivoting, in fp64 LDS.
// Output: wv_out[b][r][k] = solution, r in [0,67), k in {0(y),1(x)}.
// ---------------------------------------------------------------------------
__global__ __launch_bounds__(256) void tps_solve_kernel(
    const float* __restrict__ cp_offsets, float* __restrict__ wv_out)
{
    __shared__ double A[NA][NA];
    __shared__ double Rm[NA][NRHS];
    __shared__ double f[NA];
    __shared__ double invP;
    __shared__ int piv;
    const int tid = threadIdx.x;

    // Build lhs
    for (int idx = tid; idx < NA * NA; idx += 256) {
        int r = idx / NA, c = idx % NA;
        double val;
        if (r < NCP && c < NCP) {
            double ry = (double)(r >> 3) * (1.0 / 7.0), rx = (double)(r & 7) * (1.0 / 7.0);
            double cy = (double)(c >> 3) * (1.0 / 7.0), cx = (double)(c & 7) * (1.0 / 7.0);
            double dy = ry - cy, dx = rx - cx;
            double r2 = dy * dy + dx * dx;
            val = 0.5 * r2 * log(fmax(r2, 1e-10));
        } else if (r < NCP) {
            int k = c - NCP;
            val = (k == 0) ? (double)(r >> 3) * (1.0 / 7.0)
                : (k == 1) ? (double)(r & 7) * (1.0 / 7.0) : 1.0;
        } else if (c < NCP) {
            int k = r - NCP;
            val = (k == 0) ? (double)(c >> 3) * (1.0 / 7.0)
                : (k == 1) ? (double)(c & 7) * (1.0 / 7.0) : 1.0;
        } else {
            val = 0.0;
        }
        A[r][c] = val;
    }
    // Build rhs: rows 0..63 = cp + offset, rows 64..66 = 0
    for (int idx = tid; idx < NA * NRHS; idx += 256) {
        int r = idx / NRHS, col = idx % NRHS;
        int b = col >> 1, k = col & 1;
        double val = 0.0;
        if (r < NCP) {
            double base = (k == 0) ? (double)(r >> 3) * (1.0 / 7.0)
                                   : (double)(r & 7) * (1.0 / 7.0);
            val = base + (double)cp_offsets[(b * NCP + r) * 2 + k];
        }
        Rm[r][col] = val;
    }
    __syncthreads();

    // Gauss-Jordan with partial pivoting (zero diagonal in A => pivoting required)
    for (int p = 0; p < NA; ++p) {
        if (tid == 0) {
            int best = p; double bv = fabs(A[p][p]);
            for (int r = p + 1; r < NA; ++r) {
                double v = fabs(A[r][p]);
                if (v > bv) { bv = v; best = r; }
            }
            piv = best;
            invP = 1.0 / A[best][p];
        }
        __syncthreads();
        const int pv = piv; const double ip = invP;
        // swap rows p<->pv and normalize new row p in one pass
        for (int j = tid; j < NA + NRHS; j += 256) {
            if (j < NA) {
                double oldp = A[p][j];
                A[p][j] = A[pv][j] * ip;
                if (pv != p) A[pv][j] = oldp;
            } else {
                int jj = j - NA;
                double oldp = Rm[p][jj];
                Rm[p][jj] = Rm[pv][jj] * ip;
                if (pv != p) Rm[pv][jj] = oldp;
            }
        }
        __syncthreads();
        if (tid < NA) f[tid] = (tid == p) ? 0.0 : A[tid][p];
        __syncthreads();
        // eliminate column p from every other row
        for (int idx = tid; idx < NA * (NA + NRHS); idx += 256) {
            int r = idx / (NA + NRHS), j = idx % (NA + NRHS);
            if (r == p) continue;
            double fr = f[r];
            if (j < NA) A[r][j] -= fr * A[p][j];
            else        Rm[r][j - NA] -= fr * Rm[p][j - NA];
        }
        __syncthreads();
    }

    // A is now identity; Rm holds the solution.
    for (int idx = tid; idx < NA * NRHS; idx += 256) {
        int r = idx / NRHS, col = idx % NRHS;
        int b = col >> 1, k = col & 1;
        wv_out[(b * NA + r) * 2 + k] = (float)Rm[r][col];
    }
}

// ---------------------------------------------------------------------------
// Kernel 2: per-pixel TPS evaluation + bilinear sampling of 16 channels.
// One block per (batch, row); one thread per pixel.
// ---------------------------------------------------------------------------
__global__ __launch_bounds__(256) void tps_warp_kernel(
    const float* __restrict__ vol, const float* __restrict__ wv,
    float* __restrict__ out)
{
    const int b = blockIdx.y;
    const int y = blockIdx.x;
    const int x = threadIdx.x;

    __shared__ float wY[NCP], wX[NCP], vY[3], vX[3];
    if (threadIdx.x < NA) {
        float a0 = wv[(b * NA + threadIdx.x) * 2 + 0];
        float a1 = wv[(b * NA + threadIdx.x) * 2 + 1];
        if (threadIdx.x < NCP) { wY[threadIdx.x] = a0; wX[threadIdx.x] = a1; }
        else { vY[threadIdx.x - NCP] = a0; vX[threadIdx.x - NCP] = a1; }
    }
    __syncthreads();

    const float qy = (float)y * (1.0f / 255.0f);
    const float qx = (float)x * (1.0f / 255.0f);
    float ly = qy * vY[0] + qx * vY[1] + vY[2];
    float lx = qy * vX[0] + qx * vX[1] + vX[2];
#pragma unroll
    for (int n = 0; n < NCP; ++n) {
        const float cy = (float)(n >> 3) * (1.0f / 7.0f);
        const float cx = (float)(n & 7) * (1.0f / 7.0f);
        float dy = qy - cy, dx = qx - cx;
        float r2 = dy * dy + dx * dx;
        float ph = 0.5f * r2 * logf(fmaxf(r2, 1e-10f));
        ly += ph * wY[n];
        lx += ph * wX[n];
    }

    float fx = lx * 255.0f, fy = ly * 255.0f;
    float x0f = floorf(fx), y0f = floorf(fy);
    float wxf = fx - x0f, wyf = fy - y0f;
    int x0 = (int)x0f, y0 = (int)y0f;
    int x1 = x0 + 1, y1 = y0 + 1;
    bool vx0 = (x0 >= 0) && (x0 < WW), vx1 = (x1 >= 0) && (x1 < WW);
    bool vy0 = (y0 >= 0) && (y0 < HH), vy1 = (y1 >= 0) && (y1 < HH);
    int x0c = min(max(x0, 0), WW - 1), x1c = min(max(x1, 0), WW - 1);
    int y0c = min(max(y0, 0), HH - 1), y1c = min(max(y1, 0), HH - 1);
    float w00 = (1.f - wyf) * (1.f - wxf) * ((vy0 && vx0) ? 1.f : 0.f);
    float w01 = (1.f - wyf) * wxf         * ((vy0 && vx1) ? 1.f : 0.f);
    float w10 = wyf * (1.f - wxf)         * ((vy1 && vx0) ? 1.f : 0.f);
    float w11 = wyf * wxf                 * ((vy1 && vx1) ? 1.f : 0.f);

    const float4* vb = (const float4*)vol + (size_t)b * (HH * WW * (CC / 4));
    const float4* p00 = vb + (y0c * WW + x0c) * (CC / 4);
    const float4* p01 = vb + (y0c * WW + x1c) * (CC / 4);
    const float4* p10 = vb + (y1c * WW + x0c) * (CC / 4);
    const float4* p11 = vb + (y1c * WW + x1c) * (CC / 4);
    float4* ob = (float4*)out + ((size_t)b * HH * WW + y * WW + x) * (CC / 4);
#pragma unroll
    for (int cq = 0; cq < CC / 4; ++cq) {
        float4 a = p00[cq], bq = p01[cq], cq_ = p10[cq], dq = p11[cq];
        float4 r;
        r.x = a.x * w00 + bq.x * w01 + cq_.x * w10 + dq.x * w11;
        r.y = a.y * w00 + bq.y * w01 + cq_.y * w10 + dq.y * w11;
        r.z = a.z * w00 + bq.z * w01 + cq_.z * w10 + dq.z * w11;
        r.w = a.w * w00 + bq.w * w01 + cq_.w * w10 + dq.w * w11;
        ob[cq] = r;
    }
}

extern "C" void kernel_launch(void* const* d_in, const int* in_sizes, int n_in,
                              void* d_out, int out_size, void* d_ws, size_t ws_size,
                              hipStream_t stream)
{
    const float* vol = (const float*)d_in[0];
    const float* cpo = (const float*)d_in[1];
    float* out = (float*)d_out;
    float* wv = (float*)d_ws;  // 16*67*2 floats = 8576 B

    tps_solve_kernel<<<dim3(1), dim3(256), 0, stream>>>(cpo, wv);
    tps_warp_kernel<<<dim3(HH, BB), dim3(256), 0, stream>>>(vol, wv, out);
}

// Round 2
// 209.392 us; speedup vs baseline: 2.8004x; 2.8004x over previous
//
#include <hip/hip_runtime.h>
#include <math.h>
#include <string.h>

#define HH 256
#define WW 256
#define CC 16
#define BB 16
#define NCP 64
#define NA 67    // 64 control points + 3 affine
#define NWV (BB * NA * 2)

// ---------------------------------------------------------------------------
// Host: build the constant 67x67 TPS system and invert it (fp64, partial
// pivoting). M = inv(lhs)[:, :64]; wv0 = M @ cp (the offset-independent part
// of the solution). lhs depends only on the fixed 8x8 control grid, never on
// inputs, so this is legal host work — it runs at capture time, and the
// captured H2D memcpy re-reads the (identically recomputed) static buffer.
// ---------------------------------------------------------------------------
static void build_M(float* Mf /*[NA*NCP]*/, float* wv0 /*[NA*2]*/)
{
    static double A[NA][NA + NCP];
    for (int r = 0; r < NA; ++r) {
        for (int c = 0; c < NA; ++c) {
            double val;
            if (r < NCP && c < NCP) {
                double ry = (double)(r >> 3) / 7.0, rx = (double)(r & 7) / 7.0;
                double cy = (double)(c >> 3) / 7.0, cx = (double)(c & 7) / 7.0;
                double dy = ry - cy, dx = rx - cx;
                double r2 = dy * dy + dx * dx;
                val = 0.5 * r2 * log(r2 > 1e-10 ? r2 : 1e-10);
            } else if (r < NCP) {
                int k = c - NA + 3;  // c-64
                val = (k == 0) ? (double)(r >> 3) / 7.0
                    : (k == 1) ? (double)(r & 7) / 7.0 : 1.0;
            } else if (c < NCP) {
                int k = r - NA + 3;
                val = (k == 0) ? (double)(c >> 3) / 7.0
                    : (k == 1) ? (double)(c & 7) / 7.0 : 1.0;
            } else {
                val = 0.0;
            }
            A[r][c] = val;
        }
        for (int c = 0; c < NCP; ++c) A[r][NA + c] = (r == c) ? 1.0 : 0.0;
    }
    // Gauss-Jordan with partial pivoting (lhs has a zero diagonal block)
    for (int p = 0; p < NA; ++p) {
        int best = p; double bv = fabs(A[p][p]);
        for (int r = p + 1; r < NA; ++r) {
            double v = fabs(A[r][p]);
            if (v > bv) { bv = v; best = r; }
        }
        if (best != p)
            for (int j = 0; j < NA + NCP; ++j) {
                double t = A[p][j]; A[p][j] = A[best][j]; A[best][j] = t;
            }
        double ip = 1.0 / A[p][p];
        for (int j = 0; j < NA + NCP; ++j) A[p][j] *= ip;
        for (int r = 0; r < NA; ++r) {
            if (r == p) continue;
            double f = A[r][p];
            if (f != 0.0)
                for (int j = 0; j < NA + NCP; ++j) A[r][j] -= f * A[p][j];
        }
    }
    for (int r = 0; r < NA; ++r) {
        double s0 = 0.0, s1 = 0.0;
        for (int n = 0; n < NCP; ++n) {
            double m = A[r][NA + n];
            Mf[r * NCP + n] = (float)m;
            s0 += m * ((double)(n >> 3) / 7.0);
            s1 += m * ((double)(n & 7) / 7.0);
        }
        wv0[r * 2 + 0] = (float)s0;
        wv0[r * 2 + 1] = (float)s1;
    }
}

// ---------------------------------------------------------------------------
// Kernel 1: wv[b][r][k] = wv0[r][k] + sum_n M[r][n] * cp_offsets[b][n][k]
// 2144 outputs x 64 MACs — trivial.
// ---------------------------------------------------------------------------
__global__ __launch_bounds__(256) void tps_coef_kernel(
    const float* __restrict__ cp_offsets, const float* __restrict__ M,
    const float* __restrict__ wv0, float* __restrict__ wv)
{
    int idx = blockIdx.x * 256 + threadIdx.x;  // (b*NA + r)*2 + k
    if (idx >= NWV) return;
    int k = idx & 1;
    int r = (idx >> 1) % NA;
    int b = idx / (NA * 2);
    const float* Mr = M + r * NCP;
    const float* off = cp_offsets + b * NCP * 2 + k;
    float s = 0.f;
#pragma unroll
    for (int n = 0; n < NCP; ++n) s += Mr[n] * off[n * 2];
    wv[idx] = wv0[r * 2 + k] + s;
}

// ---------------------------------------------------------------------------
// Kernel 2: per-pixel TPS evaluation + bilinear sampling of 16 channels.
// One block per (batch, row); one thread per pixel.
// ---------------------------------------------------------------------------
__global__ __launch_bounds__(256) void tps_warp_kernel(
    const float* __restrict__ vol, const float* __restrict__ wv,
    float* __restrict__ out)
{
    const int b = blockIdx.y;
    const int y = blockIdx.x;
    const int x = threadIdx.x;

    __shared__ float wY[NCP], wX[NCP], vY[3], vX[3];
    if (threadIdx.x < NA) {
        float a0 = wv[(b * NA + threadIdx.x) * 2 + 0];
        float a1 = wv[(b * NA + threadIdx.x) * 2 + 1];
        if (threadIdx.x < NCP) { wY[threadIdx.x] = a0; wX[threadIdx.x] = a1; }
        else { vY[threadIdx.x - NCP] = a0; vX[threadIdx.x - NCP] = a1; }
    }
    __syncthreads();

    const float qy = (float)y * (1.0f / 255.0f);
    const float qx = (float)x * (1.0f / 255.0f);
    float ly = qy * vY[0] + qx * vY[1] + vY[2];
    float lx = qy * vX[0] + qx * vX[1] + vX[2];

    float dy2[8], dx2[8];
#pragma unroll
    for (int i = 0; i < 8; ++i) {
        float dy = qy - (float)i * (1.0f / 7.0f);
        float dx = qx - (float)i * (1.0f / 7.0f);
        dy2[i] = dy * dy;
        dx2[i] = dx * dx;
    }
#pragma unroll
    for (int i = 0; i < 8; ++i) {
#pragma unroll
        for (int j = 0; j < 8; ++j) {
            float r2 = dy2[i] + dx2[j];
            float ph = 0.5f * r2 * __logf(fmaxf(r2, 1e-10f));
            int n = i * 8 + j;
            ly += ph * wY[n];
            lx += ph * wX[n];
        }
    }

    float fx = lx * 255.0f, fy = ly * 255.0f;
    float x0f = floorf(fx), y0f = floorf(fy);
    float wxf = fx - x0f, wyf = fy - y0f;
    int x0 = (int)x0f, y0 = (int)y0f;
    int x1 = x0 + 1, y1 = y0 + 1;
    bool vx0 = (x0 >= 0) && (x0 < WW), vx1 = (x1 >= 0) && (x1 < WW);
    bool vy0 = (y0 >= 0) && (y0 < HH), vy1 = (y1 >= 0) && (y1 < HH);
    int x0c = min(max(x0, 0), WW - 1), x1c = min(max(x1, 0), WW - 1);
    int y0c = min(max(y0, 0), HH - 1), y1c = min(max(y1, 0), HH - 1);
    float w00 = (1.f - wyf) * (1.f - wxf) * ((vy0 && vx0) ? 1.f : 0.f);
    float w01 = (1.f - wyf) * wxf         * ((vy0 && vx1) ? 1.f : 0.f);
    float w10 = wyf * (1.f - wxf)         * ((vy1 && vx0) ? 1.f : 0.f);
    float w11 = wyf * wxf                 * ((vy1 && vx1) ? 1.f : 0.f);

    const float4* vb = (const float4*)vol + (size_t)b * (HH * WW * (CC / 4));
    const float4* p00 = vb + (y0c * WW + x0c) * (CC / 4);
    const float4* p01 = vb + (y0c * WW + x1c) * (CC / 4);
    const float4* p10 = vb + (y1c * WW + x0c) * (CC / 4);
    const float4* p11 = vb + (y1c * WW + x1c) * (CC / 4);
    float4* ob = (float4*)out + ((size_t)b * HH * WW + y * WW + x) * (CC / 4);
#pragma unroll
    for (int cq = 0; cq < CC / 4; ++cq) {
        float4 a = p00[cq], bq = p01[cq], c_ = p10[cq], dq = p11[cq];
        float4 r;
        r.x = a.x * w00 + bq.x * w01 + c_.x * w10 + dq.x * w11;
        r.y = a.y * w00 + bq.y * w01 + c_.y * w10 + dq.y * w11;
        r.z = a.z * w00 + bq.z * w01 + c_.z * w10 + dq.z * w11;
        r.w = a.w * w00 + bq.w * w01 + c_.w * w10 + dq.w * w11;
        ob[cq] = r;
    }
}

extern "C" void kernel_launch(void* const* d_in, const int* in_sizes, int n_in,
                              void* d_out, int out_size, void* d_ws, size_t ws_size,
                              hipStream_t stream)
{
    const float* vol = (const float*)d_in[0];
    const float* cpo = (const float*)d_in[1];
    float* out = (float*)d_out;

    // Persistent host staging (graph replay re-reads it); recomputed every call.
    static float h_const[NA * NCP + NA * 2];
    build_M(h_const, h_const + NA * NCP);

    float* d_M   = (float*)d_ws;                 // 4288 floats
    float* d_wv0 = d_M + NA * NCP;               // 134 floats
    float* d_wv  = d_wv0 + NA * 2;               // 2144 floats

    hipMemcpyAsync(d_M, h_const, sizeof(h_const), hipMemcpyHostToDevice, stream);

    tps_coef_kernel<<<dim3((NWV + 255) / 256), dim3(256), 0, stream>>>(
        cpo, d_M, d_wv0, d_wv);
    tps_warp_kernel<<<dim3(HH, BB), dim3(256), 0, stream>>>(vol, d_wv, out);
}

// Round 3
// 141.770 us; speedup vs baseline: 4.1362x; 1.4770x over previous
//
#include <hip/hip_runtime.h>
#include <math.h>
#include <string.h>

#define HH 256
#define WW 256
#define CC 16
#define BB 16
#define NCP 64
#define NA 67    // 64 control points + 3 affine
#define NWV (BB * NA * 2)
#define NCONST (NA * NCP + NA * 2)   // 4422 floats: M then wv0
#define CHUNK 885                    // 5 chunks of 3540 B kernarg each

// ---------------------------------------------------------------------------
// Host: build the constant 67x67 TPS system and invert it (fp64, partial
// pivoting). M = inv(lhs)[:, :64]; wv0 = M @ cp. Input-independent, so legal
// host work at capture time. Constants reach the device via by-value kernel
// args (graph-embedded) — no H2D memcpy node (130 us on pageable memory).
// ---------------------------------------------------------------------------
static void build_M(float* Mf /*[NA*NCP]*/, float* wv0 /*[NA*2]*/)
{
    static double A[NA][NA + NCP];
    for (int r = 0; r < NA; ++r) {
        for (int c = 0; c < NA; ++c) {
            double val;
            if (r < NCP && c < NCP) {
                double ry = (double)(r >> 3) / 7.0, rx = (double)(r & 7) / 7.0;
                double cy = (double)(c >> 3) / 7.0, cx = (double)(c & 7) / 7.0;
                double dy = ry - cy, dx = rx - cx;
                double r2 = dy * dy + dx * dx;
                val = 0.5 * r2 * log(r2 > 1e-10 ? r2 : 1e-10);
            } else if (r < NCP) {
                int k = c - NCP;
                val = (k == 0) ? (double)(r >> 3) / 7.0
                    : (k == 1) ? (double)(r & 7) / 7.0 : 1.0;
            } else if (c < NCP) {
                int k = r - NCP;
                val = (k == 0) ? (double)(c >> 3) / 7.0
                    : (k == 1) ? (double)(c & 7) / 7.0 : 1.0;
            } else {
                val = 0.0;
            }
            A[r][c] = val;
        }
        for (int c = 0; c < NCP; ++c) A[r][NA + c] = (r == c) ? 1.0 : 0.0;
    }
    for (int p = 0; p < NA; ++p) {
        int best = p; double bv = fabs(A[p][p]);
        for (int r = p + 1; r < NA; ++r) {
            double v = fabs(A[r][p]);
            if (v > bv) { bv = v; best = r; }
        }
        if (best != p)
            for (int j = 0; j < NA + NCP; ++j) {
                double t = A[p][j]; A[p][j] = A[best][j]; A[best][j] = t;
            }
        double ip = 1.0 / A[p][p];
        for (int j = 0; j < NA + NCP; ++j) A[p][j] *= ip;
        for (int r = 0; r < NA; ++r) {
            if (r == p) continue;
            double f = A[r][p];
            if (f != 0.0)
                for (int j = 0; j < NA + NCP; ++j) A[r][j] -= f * A[p][j];
        }
    }
    for (int r = 0; r < NA; ++r) {
        double s0 = 0.0, s1 = 0.0;
        for (int n = 0; n < NCP; ++n) {
            double m = A[r][NA + n];
            Mf[r * NCP + n] = (float)m;
            s0 += m * ((double)(n >> 3) / 7.0);
            s1 += m * ((double)(n & 7) / 7.0);
        }
        wv0[r * 2 + 0] = (float)s0;
        wv0[r * 2 + 1] = (float)s1;
    }
}

struct Chunk { float v[CHUNK]; };  // 3540 B by-value kernarg

__global__ __launch_bounds__(256) void upload_kernel(Chunk c, float* __restrict__ dst, int n)
{
    for (int i = threadIdx.x; i < n; i += 256) dst[i] = c.v[i];
}

// ---------------------------------------------------------------------------
// Kernel: wv[b][r][k] = wv0[r][k] + sum_n M[r][n] * cp_offsets[b][n][k]
// ---------------------------------------------------------------------------
__global__ __launch_bounds__(256) void tps_coef_kernel(
    const float* __restrict__ cp_offsets, const float* __restrict__ M,
    const float* __restrict__ wv0, float* __restrict__ wv)
{
    int idx = blockIdx.x * 256 + threadIdx.x;  // (b*NA + r)*2 + k
    if (idx >= NWV) return;
    int k = idx & 1;
    int r = (idx >> 1) % NA;
    int b = idx / (NA * 2);
    const float* Mr = M + r * NCP;
    const float* off = cp_offsets + b * NCP * 2 + k;
    float s = 0.f;
#pragma unroll
    for (int n = 0; n < NCP; ++n) s += Mr[n] * off[n * 2];
    wv[idx] = wv0[r * 2 + k] + s;
}

// ---------------------------------------------------------------------------
// Warp kernel, two-phase per block (one block = one image row of one batch):
//  phase 1: thread-per-pixel TPS eval -> bilinear indices + weights in LDS
//  phase 2: 4 threads per pixel (lane = pixel*4 + channel-quad) so each
//           load/store instruction's 64 lanes touch ~17 contiguous cache
//           lines instead of 64 scattered ones (4x fewer L1 transactions).
// ---------------------------------------------------------------------------
__global__ __launch_bounds__(256) void tps_warp_kernel(
    const float* __restrict__ vol, const float* __restrict__ wv,
    float* __restrict__ out)
{
    const int b = blockIdx.y;
    const int y = blockIdx.x;
    const int x = threadIdx.x;

    __shared__ float wY[NCP], wX[NCP], vA[6];
    __shared__ int   sIdx[WW][4];
    __shared__ float sW[WW][4];

    if (x < NA) {
        float a0 = wv[(b * NA + x) * 2 + 0];
        float a1 = wv[(b * NA + x) * 2 + 1];
        if (x < NCP) { wY[x] = a0; wX[x] = a1; }
        else { vA[(x - NCP) * 2] = a0; vA[(x - NCP) * 2 + 1] = a1; }
    }
    __syncthreads();

    // ---- phase 1: per-pixel TPS evaluation ----
    const float qy = (float)y * (1.0f / 255.0f);
    const float qx = (float)x * (1.0f / 255.0f);
    float ly = qy * vA[0] + qx * vA[2] + vA[4];
    float lx = qy * vA[1] + qx * vA[3] + vA[5];

    float dy2[8], dx2[8];
#pragma unroll
    for (int i = 0; i < 8; ++i) {
        float dy = qy - (float)i * (1.0f / 7.0f);
        float dx = qx - (float)i * (1.0f / 7.0f);
        dy2[i] = dy * dy;
        dx2[i] = dx * dx;
    }
#pragma unroll
    for (int i = 0; i < 8; ++i) {
#pragma unroll
        for (int j = 0; j < 8; ++j) {
            float r2 = dy2[i] + dx2[j];
            float ph = 0.5f * r2 * __logf(fmaxf(r2, 1e-10f));
            int n = i * 8 + j;
            ly += ph * wY[n];
            lx += ph * wX[n];
        }
    }

    float fx = lx * 255.0f, fy = ly * 255.0f;
    float x0f = floorf(fx), y0f = floorf(fy);
    float wxf = fx - x0f, wyf = fy - y0f;
    int x0 = (int)x0f, y0 = (int)y0f;
    int x1 = x0 + 1, y1 = y0 + 1;
    bool vx0 = (x0 >= 0) && (x0 < WW), vx1 = (x1 >= 0) && (x1 < WW);
    bool vy0 = (y0 >= 0) && (y0 < HH), vy1 = (y1 >= 0) && (y1 < HH);
    int x0c = min(max(x0, 0), WW - 1), x1c = min(max(x1, 0), WW - 1);
    int y0c = min(max(y0, 0), HH - 1), y1c = min(max(y1, 0), HH - 1);
    sW[x][0] = (1.f - wyf) * (1.f - wxf) * ((vy0 && vx0) ? 1.f : 0.f);
    sW[x][1] = (1.f - wyf) * wxf         * ((vy0 && vx1) ? 1.f : 0.f);
    sW[x][2] = wyf * (1.f - wxf)         * ((vy1 && vx0) ? 1.f : 0.f);
    sW[x][3] = wyf * wxf                 * ((vy1 && vx1) ? 1.f : 0.f);
    sIdx[x][0] = y0c * WW + x0c;
    sIdx[x][1] = y0c * WW + x1c;
    sIdx[x][2] = y1c * WW + x0c;
    sIdx[x][3] = y1c * WW + x1c;
    __syncthreads();

    // ---- phase 2: gather + blend, 4 threads per pixel ----
    const float4* vb = (const float4*)vol + (size_t)b * (HH * WW * (CC / 4));
    float4* ob = (float4*)out + ((size_t)b * HH * WW + (size_t)y * WW) * (CC / 4);
    const int cq = x & 3;
#pragma unroll
    for (int k = 0; k < 4; ++k) {
        const int p = (x >> 2) + 64 * k;
        int i00 = sIdx[p][0], i01 = sIdx[p][1], i10 = sIdx[p][2], i11 = sIdx[p][3];
        float w00 = sW[p][0], w01 = sW[p][1], w10 = sW[p][2], w11 = sW[p][3];
        float4 a  = vb[i00 * 4 + cq];
        float4 bq = vb[i01 * 4 + cq];
        float4 c_ = vb[i10 * 4 + cq];
        float4 d_ = vb[i11 * 4 + cq];
        float4 r;
        r.x = a.x * w00 + bq.x * w01 + c_.x * w10 + d_.x * w11;
        r.y = a.y * w00 + bq.y * w01 + c_.y * w10 + d_.y * w11;
        r.z = a.z * w00 + bq.z * w01 + c_.z * w10 + d_.z * w11;
        r.w = a.w * w00 + bq.w * w01 + c_.w * w10 + d_.w * w11;
        ob[p * 4 + cq] = r;
    }
}

extern "C" void kernel_launch(void* const* d_in, const int* in_sizes, int n_in,
                              void* d_out, int out_size, void* d_ws, size_t ws_size,
                              hipStream_t stream)
{
    const float* vol = (const float*)d_in[0];
    const float* cpo = (const float*)d_in[1];
    float* out = (float*)d_out;

    static float h_const[NCONST];
    build_M(h_const, h_const + NA * NCP);

    float* d_M   = (float*)d_ws;                 // 4288 floats
    float* d_wv0 = d_M + NA * NCP;               // 134 floats
    float* d_wv  = d_wv0 + NA * 2;               // 2144 floats

    // Upload constants via graph-embedded kernargs (no H2D memcpy node).
    for (int j = 0; j < 5; ++j) {
        Chunk c;
        int base = j * CHUNK;
        int n = NCONST - base; if (n > CHUNK) n = CHUNK;
        memcpy(c.v, h_const + base, n * sizeof(float));
        upload_kernel<<<dim3(1), dim3(256), 0, stream>>>(c, d_M + base, n);
    }

    tps_coef_kernel<<<dim3((NWV + 255) / 256), dim3(256), 0, stream>>>(
        cpo, d_M, d_wv0, d_wv);
    tps_warp_kernel<<<dim3(HH, BB), dim3(256), 0, stream>>>(vol, d_wv, out);
}

// Round 4
// 127.293 us; speedup vs baseline: 4.6066x; 1.1137x over previous
//
#include <hip/hip_runtime.h>
#include <math.h>
#include <string.h>

#define HH 256
#define WW 256
#define CC 16
#define BB 16
#define NCP 64
#define NA 67    // 64 control points + 3 affine

// ---------------------------------------------------------------------------
// Host: build the constant 67x67 TPS system and invert it (fp64, partial
// pivoting). M = inv(lhs)[:, :64]; wv0 = M @ cp (offset-independent part).
// Input-independent => legal host work at capture time. Constants reach the
// device as ONE by-value kernarg struct (AMDGPU passes large aggregates
// byref in the constant address space - no H2D memcpy, no upload kernels).
// ---------------------------------------------------------------------------
static void build_M(float* Mf /*[NA*NCP]*/, float* wv0 /*[NA*2]*/)
{
    static double A[NA][NA + NCP];
    for (int r = 0; r < NA; ++r) {
        for (int c = 0; c < NA; ++c) {
            double val;
            if (r < NCP && c < NCP) {
                double ry = (double)(r >> 3) / 7.0, rx = (double)(r & 7) / 7.0;
                double cy = (double)(c >> 3) / 7.0, cx = (double)(c & 7) / 7.0;
                double dy = ry - cy, dx = rx - cx;
                double r2 = dy * dy + dx * dx;
                val = 0.5 * r2 * log(r2 > 1e-10 ? r2 : 1e-10);
            } else if (r < NCP) {
                int k = c - NCP;
                val = (k == 0) ? (double)(r >> 3) / 7.0
                    : (k == 1) ? (double)(r & 7) / 7.0 : 1.0;
            } else if (c < NCP) {
                int k = r - NCP;
                val = (k == 0) ? (double)(c >> 3) / 7.0
                    : (k == 1) ? (double)(c & 7) / 7.0 : 1.0;
            } else {
                val = 0.0;
            }
            A[r][c] = val;
        }
        for (int c = 0; c < NCP; ++c) A[r][NA + c] = (r == c) ? 1.0 : 0.0;
    }
    for (int p = 0; p < NA; ++p) {
        int best = p; double bv = fabs(A[p][p]);
        for (int r = p + 1; r < NA; ++r) {
            double v = fabs(A[r][p]);
            if (v > bv) { bv = v; best = r; }
        }
        if (best != p)
            for (int j = 0; j < NA + NCP; ++j) {
                double t = A[p][j]; A[p][j] = A[best][j]; A[best][j] = t;
            }
        double ip = 1.0 / A[p][p];
        for (int j = 0; j < NA + NCP; ++j) A[p][j] *= ip;
        for (int r = 0; r < NA; ++r) {
            if (r == p) continue;
            double f = A[r][p];
            if (f != 0.0)
                for (int j = 0; j < NA + NCP; ++j) A[r][j] -= f * A[p][j];
        }
    }
    for (int r = 0; r < NA; ++r) {
        double s0 = 0.0, s1 = 0.0;
        for (int n = 0; n < NCP; ++n) {
            double m = A[r][NA + n];
            Mf[r * NCP + n] = (float)m;
            s0 += m * ((double)(n >> 3) / 7.0);
            s1 += m * ((double)(n & 7) / 7.0);
        }
        wv0[r * 2 + 0] = (float)s0;
        wv0[r * 2 + 1] = (float)s1;
    }
}

struct ConstBlob { float M[NA * NCP]; float wv0[NA * 2]; };  // 17,688 B kernarg

// ---------------------------------------------------------------------------
// Coef kernel: one block per batch. wv[b][k][r] = scale * (wv0 + M @ off).
// Pre-scales: phi rows (r<64) by 255*0.5*ln2 (so warp kernel can use v_log
// [log2] directly and skip the 0.5/ln2 muls); affine rows by 255 (so the
// warp kernel's loc is directly in pixel units).
// ---------------------------------------------------------------------------
__global__ __launch_bounds__(256) void tps_coef_kernel(
    ConstBlob cb, const float* __restrict__ cp_offsets, float* __restrict__ wv)
{
    const int b = blockIdx.x;
    const int t = threadIdx.x;
    __shared__ float sOff[NCP * 2];
    if (t < NCP * 2) sOff[t] = cp_offsets[b * NCP * 2 + t];
    __syncthreads();
    if (t >= NA * 2) return;
    const int k = t & 1;   // 0 = y-coef, 1 = x-coef
    const int r = t >> 1;
    float s = cb.wv0[r * 2 + k];
    const float* Mr = cb.M + r * NCP;
#pragma unroll
    for (int n = 0; n < NCP; ++n) s += Mr[n] * sOff[n * 2 + k];
    const float scale = (r < NCP) ? (255.0f * 0.5f * 0.69314718055994531f) : 255.0f;
    wv[(b * 2 + k) * NA + r] = s * scale;
}

// ---------------------------------------------------------------------------
// Warp kernel. Block = (row y, batch b). Phase 1: thread-per-pixel TPS eval
// with weights read through wave-uniform global pointers (-> s_load / SGPR,
// no LDS traffic in the phi loop); writes bilinear idx*4 (int4) and weights
// (float4) to LDS. Phase 2: 4 threads/pixel gather+blend (R3 structure).
// ---------------------------------------------------------------------------
__global__ __launch_bounds__(256) void tps_warp_kernel(
    const float* __restrict__ vol, const float* __restrict__ wv,
    float* __restrict__ out)
{
    const int b = blockIdx.y;
    const int y = blockIdx.x;
    const int x = threadIdx.x;

    __shared__ int4   sI[WW];
    __shared__ float4 sW[WW];

    const float* __restrict__ wY = wv + (size_t)b * 2 * NA;  // [67] y-coefs
    const float* __restrict__ wX = wY + NA;                  // [67] x-coefs

    // ---- phase 1: per-pixel TPS evaluation (pixel units) ----
    const float qy = (float)y * (1.0f / 255.0f);
    const float qx = (float)x * (1.0f / 255.0f);
    float fy = qy * wY[NCP] + qx * wY[NCP + 1] + wY[NCP + 2];
    float fx = qy * wX[NCP] + qx * wX[NCP + 1] + wX[NCP + 2];

    float dy2[8], dx2[8];
#pragma unroll
    for (int i = 0; i < 8; ++i) {
        float dy = qy - (float)i * (1.0f / 7.0f);
        float dx = qx - (float)i * (1.0f / 7.0f);
        dy2[i] = dy * dy;
        dx2[i] = dx * dx;
    }
#pragma unroll
    for (int i = 0; i < 8; ++i) {
        const float s_ = dy2[i];
#pragma unroll
        for (int j = 0; j < 8; ++j) {
            const int n = i * 8 + j;
            float r2 = s_ + dx2[j];
            float t_ = __log2f(fmaxf(r2, 1e-10f));
            float p = r2 * t_;            // phi up to the prescaled 0.5*ln2
            fy += p * wY[n];
            fx += p * wX[n];
        }
    }

    float x0f = floorf(fx), y0f = floorf(fy);
    float wxf = fx - x0f, wyf = fy - y0f;
    int x0 = (int)x0f, y0 = (int)y0f;
    int x1 = x0 + 1, y1 = y0 + 1;
    bool vx0 = (x0 >= 0) && (x0 < WW), vx1 = (x1 >= 0) && (x1 < WW);
    bool vy0 = (y0 >= 0) && (y0 < HH), vy1 = (y1 >= 0) && (y1 < HH);
    int x0c = min(max(x0, 0), WW - 1), x1c = min(max(x1, 0), WW - 1);
    int y0c = min(max(y0, 0), HH - 1), y1c = min(max(y1, 0), HH - 1);
    float4 w4;
    w4.x = (1.f - wyf) * (1.f - wxf) * ((vy0 && vx0) ? 1.f : 0.f);
    w4.y = (1.f - wyf) * wxf         * ((vy0 && vx1) ? 1.f : 0.f);
    w4.z = wyf * (1.f - wxf)         * ((vy1 && vx0) ? 1.f : 0.f);
    w4.w = wyf * wxf                 * ((vy1 && vx1) ? 1.f : 0.f);
    sW[x] = w4;
    // premultiplied by 4: float4-element index of channel-quad 0
    sI[x] = make_int4((y0c * WW + x0c) * 4, (y0c * WW + x1c) * 4,
                      (y1c * WW + x0c) * 4, (y1c * WW + x1c) * 4);
    __syncthreads();

    // ---- phase 2: gather + blend, 4 threads per pixel ----
    const float4* __restrict__ vb =
        (const float4*)vol + (size_t)b * (HH * WW * (CC / 4));
    float4* __restrict__ ob =
        (float4*)out + ((size_t)b * HH * WW + (size_t)y * WW) * (CC / 4);
    const int cq = x & 3;
#pragma unroll
    for (int k = 0; k < 4; ++k) {
        const int p = (x >> 2) + 64 * k;
        int4   I = sI[p];
        float4 Wt = sW[p];
        float4 a  = vb[I.x + cq];
        float4 bq = vb[I.y + cq];
        float4 c_ = vb[I.z + cq];
        float4 d_ = vb[I.w + cq];
        float4 r;
        r.x = a.x * Wt.x + bq.x * Wt.y + c_.x * Wt.z + d_.x * Wt.w;
        r.y = a.y * Wt.x + bq.y * Wt.y + c_.y * Wt.z + d_.y * Wt.w;
        r.z = a.z * Wt.x + bq.z * Wt.y + c_.z * Wt.z + d_.z * Wt.w;
        r.w = a.w * Wt.x + bq.w * Wt.y + c_.w * Wt.z + d_.w * Wt.w;
        ob[x + 256 * k] = r;
    }
}

extern "C" void kernel_launch(void* const* d_in, const int* in_sizes, int n_in,
                              void* d_out, int out_size, void* d_ws, size_t ws_size,
                              hipStream_t stream)
{
    const float* vol = (const float*)d_in[0];
    const float* cpo = (const float*)d_in[1];
    float* out = (float*)d_out;
    float* d_wv = (float*)d_ws;  // 16*2*67 floats

    static ConstBlob cb;
    build_M(cb.M, cb.wv0);

    tps_coef_kernel<<<dim3(BB), dim3(256), 0, stream>>>(cb, cpo, d_wv);
    tps_warp_kernel<<<dim3(HH, BB), dim3(256), 0, stream>>>(vol, d_wv, out);
}

// Round 6
// 125.899 us; speedup vs baseline: 4.6576x; 1.0111x over previous
//
#include <hip/hip_runtime.h>
#include <math.h>
#include <string.h>

#define HH 256
#define WW 256
#define CC 16
#define BB 16
#define NCP 64
#define NA 67    // 64 control points + 3 affine

typedef float f32x4 __attribute__((ext_vector_type(4)));  // for nontemporal store

// ---------------------------------------------------------------------------
// Host: build the constant 67x67 TPS system and invert it (fp64, partial
// pivoting). M = inv(lhs)[:, :64]; wv0 = M @ cp (offset-independent part).
// Input-independent => legal host work at capture time. Constants reach the
// device as ONE by-value kernarg struct (byref constant address space).
// ---------------------------------------------------------------------------
static void build_M(float* Mf /*[NA*NCP]*/, float* wv0 /*[NA*2]*/)
{
    static double A[NA][NA + NCP];
    for (int r = 0; r < NA; ++r) {
        for (int c = 0; c < NA; ++c) {
            double val;
            if (r < NCP && c < NCP) {
                double ry = (double)(r >> 3) / 7.0, rx = (double)(r & 7) / 7.0;
                double cy = (double)(c >> 3) / 7.0, cx = (double)(c & 7) / 7.0;
                double dy = ry - cy, dx = rx - cx;
                double r2 = dy * dy + dx * dx;
                val = 0.5 * r2 * log(r2 > 1e-10 ? r2 : 1e-10);
            } else if (r < NCP) {
                int k = c - NCP;
                val = (k == 0) ? (double)(r >> 3) / 7.0
                    : (k == 1) ? (double)(r & 7) / 7.0 : 1.0;
            } else if (c < NCP) {
                int k = r - NCP;
                val = (k == 0) ? (double)(c >> 3) / 7.0
                    : (k == 1) ? (double)(c & 7) / 7.0 : 1.0;
            } else {
                val = 0.0;
            }
            A[r][c] = val;
        }
        for (int c = 0; c < NCP; ++c) A[r][NA + c] = (r == c) ? 1.0 : 0.0;
    }
    for (int p = 0; p < NA; ++p) {
        int best = p; double bv = fabs(A[p][p]);
        for (int r = p + 1; r < NA; ++r) {
            double v = fabs(A[r][p]);
            if (v > bv) { bv = v; best = r; }
        }
        if (best != p)
            for (int j = 0; j < NA + NCP; ++j) {
                double t = A[p][j]; A[p][j] = A[best][j]; A[best][j] = t;
            }
        double ip = 1.0 / A[p][p];
        for (int j = 0; j < NA + NCP; ++j) A[p][j] *= ip;
        for (int r = 0; r < NA; ++r) {
            if (r == p) continue;
            double f = A[r][p];
            if (f != 0.0)
                for (int j = 0; j < NA + NCP; ++j) A[r][j] -= f * A[p][j];
        }
    }
    for (int r = 0; r < NA; ++r) {
        double s0 = 0.0, s1 = 0.0;
        for (int n = 0; n < NCP; ++n) {
            double m = A[r][NA + n];
            Mf[r * NCP + n] = (float)m;
            s0 += m * ((double)(n >> 3) / 7.0);
            s1 += m * ((double)(n & 7) / 7.0);
        }
        wv0[r * 2 + 0] = (float)s0;
        wv0[r * 2 + 1] = (float)s1;
    }
}

struct ConstBlob { float M[NA * NCP]; float wv0[NA * 2]; };  // 17,688 B kernarg

// ---------------------------------------------------------------------------
// Coef kernel: one block per batch. wv[b][k][r] = scale * (wv0 + M @ off).
// Pre-scales: phi rows by 255*0.5*ln2 (warp kernel uses v_log [log2] raw);
// affine rows by 255 (loc directly in pixel units).
// ---------------------------------------------------------------------------
__global__ __launch_bounds__(256) void tps_coef_kernel(
    ConstBlob cb, const float* __restrict__ cp_offsets, float* __restrict__ wv)
{
    const int b = blockIdx.x;
    const int t = threadIdx.x;
    __shared__ float sOff[NCP * 2];
    if (t < NCP * 2) sOff[t] = cp_offsets[b * NCP * 2 + t];
    __syncthreads();
    if (t >= NA * 2) return;
    const int k = t & 1;   // 0 = y-coef, 1 = x-coef
    const int r = t >> 1;
    float s = cb.wv0[r * 2 + k];
    const float* Mr = cb.M + r * NCP;
#pragma unroll
    for (int n = 0; n < NCP; ++n) s += Mr[n] * sOff[n * 2 + k];
    const float scale = (r < NCP) ? (255.0f * 0.5f * 0.69314718055994531f) : 255.0f;
    wv[(b * 2 + k) * NA + r] = s * scale;
}

// ---------------------------------------------------------------------------
// Warp kernel. 1-D grid of 4096 blocks, XCD-aware decode: id = xcd + 8*j,
// b = 2*xcd + (j>>8), y = j&255  (bijective). Each XCD owns 2 whole batches
// with contiguous rows, so the one-row overlap between adjacent rows'
// bilinear footprints is an L2 hit instead of a second HBM fetch.
// Phase 1: thread-per-pixel TPS eval, weights via wave-uniform s_loads.
// Phase 2: 4 threads/pixel gather+blend; nontemporal stores (write-once out
// must not evict vol lines from the 4 MB per-XCD L2).
// ---------------------------------------------------------------------------
__global__ __launch_bounds__(256) void tps_warp_kernel(
    const float* __restrict__ vol, const float* __restrict__ wv,
    float* __restrict__ out)
{
    const int id = blockIdx.x;
    const int xcd = id & 7;
    const int j = id >> 3;
    const int b = (xcd << 1) | (j >> 8);
    const int y = j & 255;
    const int x = threadIdx.x;

    __shared__ int4   sI[WW];
    __shared__ float4 sW[WW];

    const float* __restrict__ wY = wv + (size_t)b * 2 * NA;  // [67] y-coefs
    const float* __restrict__ wX = wY + NA;                  // [67] x-coefs

    // ---- phase 1: per-pixel TPS evaluation (pixel units) ----
    const float qy = (float)y * (1.0f / 255.0f);
    const float qx = (float)x * (1.0f / 255.0f);
    float fy = qy * wY[NCP] + qx * wY[NCP + 1] + wY[NCP + 2];
    float fx = qy * wX[NCP] + qx * wX[NCP + 1] + wX[NCP + 2];

    float dy2[8], dx2[8];
#pragma unroll
    for (int i = 0; i < 8; ++i) {
        float dy = qy - (float)i * (1.0f / 7.0f);
        float dx = qx - (float)i * (1.0f / 7.0f);
        dy2[i] = dy * dy;
        dx2[i] = dx * dx;
    }
#pragma unroll
    for (int i = 0; i < 8; ++i) {
        const float s_ = dy2[i];
#pragma unroll
        for (int jj = 0; jj < 8; ++jj) {
            const int n = i * 8 + jj;
            float r2 = s_ + dx2[jj];
            float t_ = __log2f(fmaxf(r2, 1e-10f));
            float p = r2 * t_;            // phi up to the prescaled 0.5*ln2
            fy += p * wY[n];
            fx += p * wX[n];
        }
    }

    float x0f = floorf(fx), y0f = floorf(fy);
    float wxf = fx - x0f, wyf = fy - y0f;
    int x0 = (int)x0f, y0 = (int)y0f;
    int x1 = x0 + 1, y1 = y0 + 1;
    bool vx0 = (x0 >= 0) && (x0 < WW), vx1 = (x1 >= 0) && (x1 < WW);
    bool vy0 = (y0 >= 0) && (y0 < HH), vy1 = (y1 >= 0) && (y1 < HH);
    int x0c = min(max(x0, 0), WW - 1), x1c = min(max(x1, 0), WW - 1);
    int y0c = min(max(y0, 0), HH - 1), y1c = min(max(y1, 0), HH - 1);
    float4 w4;
    w4.x = (1.f - wyf) * (1.f - wxf) * ((vy0 && vx0) ? 1.f : 0.f);
    w4.y = (1.f - wyf) * wxf         * ((vy0 && vx1) ? 1.f : 0.f);
    w4.z = wyf * (1.f - wxf)         * ((vy1 && vx0) ? 1.f : 0.f);
    w4.w = wyf * wxf                 * ((vy1 && vx1) ? 1.f : 0.f);
    sW[x] = w4;
    // premultiplied by 4: float4-element index of channel-quad 0
    sI[x] = make_int4((y0c * WW + x0c) * 4, (y0c * WW + x1c) * 4,
                      (y1c * WW + x0c) * 4, (y1c * WW + x1c) * 4);
    __syncthreads();

    // ---- phase 2: gather + blend, 4 threads per pixel ----
    const float4* __restrict__ vb =
        (const float4*)vol + (size_t)b * (HH * WW * (CC / 4));
    f32x4* __restrict__ ob =
        (f32x4*)out + ((size_t)b * HH * WW + (size_t)y * WW) * (CC / 4);
    const int cq = x & 3;
#pragma unroll
    for (int k = 0; k < 4; ++k) {
        const int p = (x >> 2) + 64 * k;
        int4   I = sI[p];
        float4 Wt = sW[p];
        float4 a  = vb[I.x + cq];
        float4 bq = vb[I.y + cq];
        float4 c_ = vb[I.z + cq];
        float4 d_ = vb[I.w + cq];
        f32x4 r;
        r.x = a.x * Wt.x + bq.x * Wt.y + c_.x * Wt.z + d_.x * Wt.w;
        r.y = a.y * Wt.x + bq.y * Wt.y + c_.y * Wt.z + d_.y * Wt.w;
        r.z = a.z * Wt.x + bq.z * Wt.y + c_.z * Wt.z + d_.z * Wt.w;
        r.w = a.w * Wt.x + bq.w * Wt.y + c_.w * Wt.z + d_.w * Wt.w;
        __builtin_nontemporal_store(r, &ob[x + 256 * k]);
    }
}

extern "C" void kernel_launch(void* const* d_in, const int* in_sizes, int n_in,
                              void* d_out, int out_size, void* d_ws, size_t ws_size,
                              hipStream_t stream)
{
    const float* vol = (const float*)d_in[0];
    const float* cpo = (const float*)d_in[1];
    float* out = (float*)d_out;
    float* d_wv = (float*)d_ws;  // 16*2*67 floats

    static ConstBlob cb;
    build_M(cb.M, cb.wv0);

    tps_coef_kernel<<<dim3(BB), dim3(256), 0, stream>>>(cb, cpo, d_wv);
    tps_warp_kernel<<<dim3(HH * BB), dim3(256), 0, stream>>>(vol, d_wv, out);
}